// Round 4
// baseline (1674.246 us; speedup 1.0000x reference)
//
#include <hip/hip_runtime.h>

#define BB 4096
#define NN 128
#define FF 28
#define HH 512
#define GG 8
#define NI 4
#define SELFW 36
#define XROW 3620       // SELF + N*F
#define IG_BASE 36
#define OG_BASE 14372   // 36 + 4*128*28

// ---------------- threefry2x32, JAX partitionable random_bits ------------------------
// key = PRNGKey(42) = [0, 42]. For a 32-bit draw of flat index i (< 2^32):
// inputs (x0, x1) = (hi32(i), lo32(i)) = (0, i); output = out0 ^ out1.
__device__ __forceinline__ unsigned rotl32(unsigned x, unsigned r) {
    return (x << r) | (x >> (32u - r));
}

__device__ __forceinline__ unsigned threefry_bits(unsigned idx) {
    unsigned x0 = 0u, x1 = idx;
    const unsigned k0 = 0u, k1 = 42u, k2 = 0x1BD11BDAu ^ 0u ^ 42u;
    x0 += k0; x1 += k1;
#define R4(a,b,c,d) \
    x0 += x1; x1 = rotl32(x1,(a)); x1 ^= x0; \
    x0 += x1; x1 = rotl32(x1,(b)); x1 ^= x0; \
    x0 += x1; x1 = rotl32(x1,(c)); x1 ^= x0; \
    x0 += x1; x1 = rotl32(x1,(d)); x1 ^= x0;
    R4(13,15,26,6)   x0 += k1; x1 += k2 + 1u;
    R4(17,29,16,24)  x0 += k2; x1 += k0 + 2u;
    R4(13,15,26,6)   x0 += k0; x1 += k1 + 3u;
    R4(17,29,16,24)  x0 += k1; x1 += k2 + 4u;
    R4(13,15,26,6)   x0 += k2; x1 += k0 + 5u;
#undef R4
    return x0 ^ x1;
}

__device__ __forceinline__ float gumbel_at(unsigned idx) {
    unsigned bits = threefry_bits(idx);
    // jax.random.uniform(minval=tiny, maxval=1): (bits>>9)|0x3f800000, -1.0, max(tiny,.)
    float f = __uint_as_float((bits >> 9) | 0x3f800000u) - 1.0f;
    float u = fmaxf(f, 1.17549435e-38f);
    return -logf(-logf(u));
}

// ---------------- K1: routing (h -> logits -> gumbel argmax -> masks/grp) ------------
// lane-per-(b,n); W1^T, W2, b1 staged in LDS (broadcast reads, conflict-free).
__global__ __launch_bounds__(256, 2) void k_route(
    const float* __restrict__ x, const float* __restrict__ W1,
    const float* __restrict__ b1, const float* __restrict__ W2,
    const float* __restrict__ b2,
    unsigned char* __restrict__ grp, unsigned char* __restrict__ grpT,
    float* __restrict__ ig_mask, float* __restrict__ og_mask)
{
    __shared__ float w1t[HH * FF];   // [j][f] transposed, rows 112B (16B aligned)
    __shared__ float w2s[HH * GG];   // [j][g], rows 32B
    __shared__ float b1s[HH];

    for (int i = threadIdx.x; i < FF * HH; i += 256) {
        int f = i / HH, j = i % HH;          // coalesced read of W1[f][j]
        w1t[j * FF + f] = W1[i];
    }
    for (int i = threadIdx.x; i < HH * GG; i += 256) w2s[i] = W2[i];
    for (int i = threadIdx.x; i < HH; i += 256) b1s[i] = b1[i];
    __syncthreads();

    float b2r[GG];
#pragma unroll
    for (int g = 0; g < GG; ++g) b2r[g] = b2[g];

    int tid = blockIdx.x * 256 + threadIdx.x;
    int nthreads = gridDim.x * 256;
    for (int item = tid; item < BB * NN; item += nthreads) {
        int b = item >> 7, n = item & 127;
        const float4* op = (const float4*)(x + (size_t)b * XROW + SELFW + n * FF);
        float o[FF];
#pragma unroll
        for (int q = 0; q < 7; ++q) {
            float4 v = op[q];
            o[4*q+0] = v.x; o[4*q+1] = v.y; o[4*q+2] = v.z; o[4*q+3] = v.w;
        }
        float acc[GG];
#pragma unroll
        for (int g = 0; g < GG; ++g) acc[g] = 0.0f;

        for (int j = 0; j < HH; ++j) {
            const float4* wr = (const float4*)(w1t + j * FF);
            float h = 0.0f;                       // serial f-ascending chain
#pragma unroll
            for (int q = 0; q < 7; ++q) {
                float4 w = wr[q];
                h = fmaf(o[4*q+0], w.x, h);
                h = fmaf(o[4*q+1], w.y, h);
                h = fmaf(o[4*q+2], w.z, h);
                h = fmaf(o[4*q+3], w.w, h);
            }
            h += b1s[j];                           // bias after matmul (XLA order)
            h = fmaxf(h, 0.0f);
            const float4* w2r = (const float4*)(w2s + j * GG);
            float4 wa = w2r[0], wb = w2r[1];
            acc[0] = fmaf(h, wa.x, acc[0]);
            acc[1] = fmaf(h, wa.y, acc[1]);
            acc[2] = fmaf(h, wa.z, acc[2]);
            acc[3] = fmaf(h, wa.w, acc[3]);
            acc[4] = fmaf(h, wb.x, acc[4]);
            acc[5] = fmaf(h, wb.y, acc[5]);
            acc[6] = fmaf(h, wb.z, acc[6]);
            acc[7] = fmaf(h, wb.w, acc[7]);
        }

        // z_g = logits + b2 + gumbel; TAU == 1.0 so the divide is identity.
        int best = 0;
        float bz = acc[0] + b2r[0] + gumbel_at(((unsigned)item << 3) + 0u);
#pragma unroll
        for (int g = 1; g < GG; ++g) {
            float z = acc[g] + b2r[g] + gumbel_at(((unsigned)item << 3) + (unsigned)g);
            if (z > bz) { bz = z; best = g; }      // strict > keeps first max (jnp.argmax)
        }

        grp[item] = (unsigned char)best;
        grpT[(size_t)n * BB + b] = (unsigned char)best;
        // y = stop_grad(hard - soft) + soft == hard (±1 ulp): write 1.0f into zeroed mask
        if (best < NI) ig_mask[(size_t)b * 512 + best * 128 + n] = 1.0f;
        else           og_mask[(size_t)b * 512 + (best - NI) * 128 + n] = 1.0f;
    }
}

// ---------------- K2: ogroup_em[b,4,28] = sum_n [grp==4+g] * o[b,n,f] ---------------
__global__ __launch_bounds__(256) void k_ogem(
    const float* __restrict__ x, const unsigned char* __restrict__ grp,
    float* __restrict__ og_em)
{
    int t = threadIdx.x;
    int bl = t >> 5, f = t & 31;                 // 8 b per block, 32 slots (4 idle)
    size_t b = (size_t)blockIdx.x * 8 + bl;
    if (f >= FF) return;
    const unsigned char* gp = grp + b * NN;
    const float* xp = x + b * XROW + SELFW;
    float a0 = 0.f, a1 = 0.f, a2 = 0.f, a3 = 0.f;
    for (int n = 0; n < NN; ++n) {
        int g = gp[n];
        float v = xp[n * FF + f];
        a0 += (g == 4) ? v : 0.0f;               // cndmask, no dynamic reg indexing
        a1 += (g == 5) ? v : 0.0f;
        a2 += (g == 6) ? v : 0.0f;
        a3 += (g == 7) ? v : 0.0f;
    }
    float* e = og_em + b * 112 + f;
    e[0] = a0; e[28] = a1; e[56] = a2; e[84] = a3;
}

// ---------------- K3: dense part out = ba + self@Wa[0:36] + og_em@Wa[14372:] --------
__global__ __launch_bounds__(256) void k_dense(
    const float* __restrict__ x, const float* __restrict__ og_em,
    const float* __restrict__ Wa, const float* __restrict__ ba,
    float* __restrict__ out)
{
    __shared__ float As[16][148];
    int t = threadIdx.x;
    size_t b0 = (size_t)blockIdx.x * 16;
    for (int i = t; i < 16 * 148; i += 256) {
        int bl = i / 148, k = i % 148;
        As[bl][k] = (k < SELFW) ? x[(b0 + bl) * XROW + k]
                                : og_em[(b0 + bl) * 112 + (k - SELFW)];
    }
    __syncthreads();
    int lane = t & 63, wv = t >> 6;
    int h0 = lane * 8;
    float acc[4][8];
#pragma unroll
    for (int i = 0; i < 4; ++i)
#pragma unroll
        for (int j = 0; j < 8; ++j) acc[i][j] = 0.0f;

    for (int k = 0; k < 148; ++k) {
        int row = (k < SELFW) ? k : (OG_BASE + k - SELFW);
        const float4* wr = (const float4*)(Wa + (size_t)row * HH + h0);
        float4 wA = wr[0], wB = wr[1];
#pragma unroll
        for (int i = 0; i < 4; ++i) {
            float a = As[wv * 4 + i][k];
            acc[i][0] = fmaf(a, wA.x, acc[i][0]);
            acc[i][1] = fmaf(a, wA.y, acc[i][1]);
            acc[i][2] = fmaf(a, wA.z, acc[i][2]);
            acc[i][3] = fmaf(a, wA.w, acc[i][3]);
            acc[i][4] = fmaf(a, wB.x, acc[i][4]);
            acc[i][5] = fmaf(a, wB.y, acc[i][5]);
            acc[i][6] = fmaf(a, wB.z, acc[i][6]);
            acc[i][7] = fmaf(a, wB.w, acc[i][7]);
        }
    }
    float4 baA = *(const float4*)(ba + h0);
    float4 baB = *(const float4*)(ba + h0 + 4);
    float bav[8] = {baA.x, baA.y, baA.z, baA.w, baB.x, baB.y, baB.z, baB.w};
#pragma unroll
    for (int i = 0; i < 4; ++i) {
        float* opt = out + (b0 + wv * 4 + i) * HH + h0;
#pragma unroll
        for (int j = 0; j < 8; ++j) opt[j] = acc[i][j] + bav[j];
    }
}

// ---------------- K4: igroup routed contraction, out += o[b,n] @ Wa_ig[grp,n] -------
// block = (64 b) x (64 h) register tile; per n stage 4 expert slices (28x64) in LDS.
__global__ __launch_bounds__(256, 2) void k_ig(
    const float* __restrict__ x, const unsigned char* __restrict__ grpT,
    const float* __restrict__ Wa, float* __restrict__ out)
{
    __shared__ float Ws[NI][FF][64];             // 28.7 KB
    __shared__ float Os[64][FF];                 // 7.2 KB (rows 112B, 16B aligned)
    __shared__ unsigned char Gs[64];
    int t = threadIdx.x;
    size_t b0 = (size_t)(blockIdx.x >> 3) * 64;
    int h0 = (blockIdx.x & 7) * 64;
    int lane = t & 63, wv = t >> 6;
    float acc[16];
#pragma unroll
    for (int i = 0; i < 16; ++i) acc[i] = 0.0f;

    for (int n = 0; n < NN; ++n) {
        __syncthreads();                          // previous-iteration LDS reads done
        if (t < 64) Gs[t] = grpT[(size_t)n * BB + b0 + t];
        for (int i = t; i < NI * FF * 64; i += 256) {
            int g = i / (FF * 64);
            int r = (i / 64) % FF;
            int c = i & 63;
            Ws[g][r][c] = Wa[(size_t)(IG_BASE + g * (NN * FF) + n * FF + r) * HH + h0 + c];
        }
        for (int i = t; i < 64 * FF; i += 256) {
            int bl = i / FF, f = i % FF;
            Os[bl][f] = x[(b0 + bl) * XROW + SELFW + n * FF + f];
        }
        __syncthreads();
#pragma unroll                                    // FULL unroll: static acc[] indexing
        for (int i = 0; i < 16; ++i) {
            int bl = wv * 16 + i;
            int gb = Gs[bl];                      // wave-uniform -> uniform branch
            if (gb < NI) {
                const float* wp = &Ws[gb][0][lane];
                const float* opr = &Os[bl][0];
                float a = acc[i];
#pragma unroll
                for (int f = 0; f < FF; ++f) a = fmaf(opr[f], wp[(size_t)f * 64], a);
                acc[i] = a;
            }
        }
    }
#pragma unroll
    for (int i = 0; i < 16; ++i) {
        size_t idx = (b0 + wv * 16 + i) * HH + h0 + lane;
        out[idx] += acc[i];                       // tiles partition out: no races
    }
}

// ---------------- launcher ----------------------------------------------------------
extern "C" void kernel_launch(void* const* d_in, const int* in_sizes, int n_in,
                              void* d_out, int out_size, void* d_ws, size_t ws_size,
                              hipStream_t stream)
{
    const float* x  = (const float*)d_in[0];
    const float* W1 = (const float*)d_in[1];
    const float* b1 = (const float*)d_in[2];
    const float* W2 = (const float*)d_in[3];
    const float* b2 = (const float*)d_in[4];
    const float* Wa = (const float*)d_in[5];
    const float* ba = (const float*)d_in[6];

    float* out     = (float*)d_out;                       // [4096,512]
    float* ig_mask = out + (size_t)BB * HH;               // [4096,4,128]
    float* og_mask = ig_mask + (size_t)BB * NI * NN;      // [4096,4,128]

    unsigned char* grp  = (unsigned char*)d_ws;           // [4096*128]
    unsigned char* grpT = grp + (size_t)BB * NN;          // [128*4096]
    float* og_em = (float*)(grpT + (size_t)BB * NN);      // [4096,4,28]

    // masks are one-hot scatters into a zeroed field
    hipMemsetAsync(ig_mask, 0, (size_t)2 * BB * NI * NN * sizeof(float), stream);

    k_route<<<512, 256, 0, stream>>>(x, W1, b1, W2, b2, grp, grpT, ig_mask, og_mask);
    k_ogem <<<512, 256, 0, stream>>>(x, grp, og_em);
    k_dense<<<256, 256, 0, stream>>>(x, og_em, Wa, ba, out);
    k_ig   <<<512, 256, 0, stream>>>(x, grpT, Wa, out);
}

// Round 5
// 701.980 us; speedup vs baseline: 2.3850x; 2.3850x over previous
//
#include <hip/hip_runtime.h>
#include <hip/hip_bf16.h>

#define BB 4096
#define NN 128
#define FF 28
#define HH 512
#define GG 8
#define NI 4
#define SELFW 36
#define XROW 3620       // SELF + N*F
#define IG_BASE 36
#define OG_BASE 14372   // 36 + 4*128*28

typedef short v8s __attribute__((ext_vector_type(8)));
typedef float v16f __attribute__((ext_vector_type(16)));
typedef unsigned v4u __attribute__((ext_vector_type(4)));

__device__ __forceinline__ unsigned rotl32(unsigned x, unsigned r) {
    return (x << r) | (x >> (32u - r));
}

// threefry2x32, JAX partitionable random_bits; key = PRNGKey(42) = [0,42]
__device__ __forceinline__ unsigned threefry_bits(unsigned idx) {
    unsigned x0 = 0u, x1 = idx;
    const unsigned k0 = 0u, k1 = 42u, k2 = 0x1BD11BDAu ^ 0u ^ 42u;
    x0 += k0; x1 += k1;
#define R4(a,b,c,d) \
    x0 += x1; x1 = rotl32(x1,(a)); x1 ^= x0; \
    x0 += x1; x1 = rotl32(x1,(b)); x1 ^= x0; \
    x0 += x1; x1 = rotl32(x1,(c)); x1 ^= x0; \
    x0 += x1; x1 = rotl32(x1,(d)); x1 ^= x0;
    R4(13,15,26,6)   x0 += k1; x1 += k2 + 1u;
    R4(17,29,16,24)  x0 += k2; x1 += k0 + 2u;
    R4(13,15,26,6)   x0 += k0; x1 += k1 + 3u;
    R4(17,29,16,24)  x0 += k1; x1 += k2 + 4u;
    R4(13,15,26,6)   x0 += k2; x1 += k0 + 5u;
#undef R4
    return x0 ^ x1;
}

__device__ __forceinline__ float gumbel_at(unsigned idx) {
    unsigned bits = threefry_bits(idx);
    float f = __uint_as_float((bits >> 9) | 0x3f800000u) - 1.0f;
    float u = fmaxf(f, 1.17549435e-38f);
    return -logf(-logf(u));
}

__device__ __forceinline__ unsigned pk2(float a, float b) {
    __hip_bfloat162 h = __float22bfloat162_rn(make_float2(a, b));
    union { __hip_bfloat162 h; unsigned u; } c; c.h = h; return c.u;
}

__device__ __forceinline__ v8s as8s(v4u v) {
    union { v4u u; v8s s; } c; c.u = v; return c.s;
}

// ---------------- K0: Wa_ig -> Wbt[g][n][h][f(32 pad)] bf16 ------------------------
__global__ __launch_bounds__(256) void k_prep(
    const float* __restrict__ Wa, unsigned short* __restrict__ Wbt)
{
    int tid = blockIdx.x * 256 + threadIdx.x;     // 0..262143 = (g*128+n)*512 + h
    int h = tid & 511, gn = tid >> 9;
    const float* src = Wa + (size_t)(IG_BASE + gn * FF) * HH + h;  // src[f*512]
    unsigned w[16];
#pragma unroll
    for (int q = 0; q < 14; ++q) w[q] = pk2(src[(2*q) * HH], src[(2*q+1) * HH]);
    w[14] = 0u; w[15] = 0u;                        // f = 28..31 zero pad
    v4u* dst = (v4u*)(Wbt + (size_t)tid * 32);
    dst[0] = v4u{w[0],  w[1],  w[2],  w[3]};
    dst[1] = v4u{w[4],  w[5],  w[6],  w[7]};
    dst[2] = v4u{w[8],  w[9],  w[10], w[11]};
    dst[3] = v4u{w[12], w[13], w[14], w[15]};
}

// ---------------- K1: routing (h -> logits -> gumbel argmax -> masks/grp) ------------
__global__ __launch_bounds__(256, 2) void k_route(
    const float* __restrict__ x, const float* __restrict__ W1,
    const float* __restrict__ b1, const float* __restrict__ W2,
    const float* __restrict__ b2,
    unsigned char* __restrict__ grp, unsigned char* __restrict__ grpT,
    float* __restrict__ ig_mask, float* __restrict__ og_mask)
{
    __shared__ float w1t[HH * FF];
    __shared__ float w2s[HH * GG];
    __shared__ float b1s[HH];

    for (int i = threadIdx.x; i < FF * HH; i += 256) {
        int f = i / HH, j = i % HH;
        w1t[j * FF + f] = W1[i];
    }
    for (int i = threadIdx.x; i < HH * GG; i += 256) w2s[i] = W2[i];
    for (int i = threadIdx.x; i < HH; i += 256) b1s[i] = b1[i];
    __syncthreads();

    float b2r[GG];
#pragma unroll
    for (int g = 0; g < GG; ++g) b2r[g] = b2[g];

    int tid = blockIdx.x * 256 + threadIdx.x;
    int nthreads = gridDim.x * 256;
    for (int item = tid; item < BB * NN; item += nthreads) {
        int b = item >> 7, n = item & 127;
        const float4* op = (const float4*)(x + (size_t)b * XROW + SELFW + n * FF);
        float o[FF];
#pragma unroll
        for (int q = 0; q < 7; ++q) {
            float4 v = op[q];
            o[4*q+0] = v.x; o[4*q+1] = v.y; o[4*q+2] = v.z; o[4*q+3] = v.w;
        }
        float acc[GG];
#pragma unroll
        for (int g = 0; g < GG; ++g) acc[g] = 0.0f;

        for (int j = 0; j < HH; ++j) {
            const float4* wr = (const float4*)(w1t + j * FF);
            float h = 0.0f;
#pragma unroll
            for (int q = 0; q < 7; ++q) {
                float4 w = wr[q];
                h = fmaf(o[4*q+0], w.x, h);
                h = fmaf(o[4*q+1], w.y, h);
                h = fmaf(o[4*q+2], w.z, h);
                h = fmaf(o[4*q+3], w.w, h);
            }
            h += b1s[j];
            h = fmaxf(h, 0.0f);
            const float4* w2r = (const float4*)(w2s + j * GG);
            float4 wa = w2r[0], wb = w2r[1];
            acc[0] = fmaf(h, wa.x, acc[0]);
            acc[1] = fmaf(h, wa.y, acc[1]);
            acc[2] = fmaf(h, wa.z, acc[2]);
            acc[3] = fmaf(h, wa.w, acc[3]);
            acc[4] = fmaf(h, wb.x, acc[4]);
            acc[5] = fmaf(h, wb.y, acc[5]);
            acc[6] = fmaf(h, wb.z, acc[6]);
            acc[7] = fmaf(h, wb.w, acc[7]);
        }

        int best = 0;
        float bz = acc[0] + b2r[0] + gumbel_at(((unsigned)item << 3) + 0u);
#pragma unroll
        for (int g = 1; g < GG; ++g) {
            float z = acc[g] + b2r[g] + gumbel_at(((unsigned)item << 3) + (unsigned)g);
            if (z > bz) { bz = z; best = g; }
        }

        grp[item] = (unsigned char)best;
        grpT[(size_t)n * BB + b] = (unsigned char)best;
        if (best < NI) ig_mask[(size_t)b * 512 + best * 128 + n] = 1.0f;
        else           og_mask[(size_t)b * 512 + (best - NI) * 128 + n] = 1.0f;
    }
}

// ---------------- K2: ogroup_em[b,4,28] = sum_n [grp==4+g] * o[b,n,f] ---------------
__global__ __launch_bounds__(256) void k_ogem(
    const float* __restrict__ x, const unsigned char* __restrict__ grp,
    float* __restrict__ og_em)
{
    int t = threadIdx.x;
    int bl = t >> 5, f = t & 31;
    size_t b = (size_t)blockIdx.x * 8 + bl;
    if (f >= FF) return;
    const unsigned char* gp = grp + b * NN;
    const float* xp = x + b * XROW + SELFW;
    float a0 = 0.f, a1 = 0.f, a2 = 0.f, a3 = 0.f;
    for (int n = 0; n < NN; ++n) {
        int g = gp[n];
        float v = xp[n * FF + f];
        a0 += (g == 4) ? v : 0.0f;
        a1 += (g == 5) ? v : 0.0f;
        a2 += (g == 6) ? v : 0.0f;
        a3 += (g == 7) ? v : 0.0f;
    }
    float* e = og_em + b * 112 + f;
    e[0] = a0; e[28] = a1; e[56] = a2; e[84] = a3;
}

// ---------------- K3: dense part out = ba + self@Wa[0:36] + og_em@Wa[14372:] --------
__global__ __launch_bounds__(256) void k_dense(
    const float* __restrict__ x, const float* __restrict__ og_em,
    const float* __restrict__ Wa, const float* __restrict__ ba,
    float* __restrict__ out)
{
    __shared__ float As[16][148];
    int t = threadIdx.x;
    size_t b0 = (size_t)blockIdx.x * 16;
    for (int i = t; i < 16 * 148; i += 256) {
        int bl = i / 148, k = i % 148;
        As[bl][k] = (k < SELFW) ? x[(b0 + bl) * XROW + k]
                                : og_em[(b0 + bl) * 112 + (k - SELFW)];
    }
    __syncthreads();
    int lane = t & 63, wv = t >> 6;
    int h0 = lane * 8;
    float acc[4][8];
#pragma unroll
    for (int i = 0; i < 4; ++i)
#pragma unroll
        for (int j = 0; j < 8; ++j) acc[i][j] = 0.0f;

    for (int k = 0; k < 148; ++k) {
        int row = (k < SELFW) ? k : (OG_BASE + k - SELFW);
        const float4* wr = (const float4*)(Wa + (size_t)row * HH + h0);
        float4 wA = wr[0], wB = wr[1];
#pragma unroll
        for (int i = 0; i < 4; ++i) {
            float a = As[wv * 4 + i][k];
            acc[i][0] = fmaf(a, wA.x, acc[i][0]);
            acc[i][1] = fmaf(a, wA.y, acc[i][1]);
            acc[i][2] = fmaf(a, wA.z, acc[i][2]);
            acc[i][3] = fmaf(a, wA.w, acc[i][3]);
            acc[i][4] = fmaf(a, wB.x, acc[i][4]);
            acc[i][5] = fmaf(a, wB.y, acc[i][5]);
            acc[i][6] = fmaf(a, wB.z, acc[i][6]);
            acc[i][7] = fmaf(a, wB.w, acc[i][7]);
        }
    }
    float4 baA = *(const float4*)(ba + h0);
    float4 baB = *(const float4*)(ba + h0 + 4);
    float bav[8] = {baA.x, baA.y, baA.z, baA.w, baB.x, baB.y, baB.z, baB.w};
#pragma unroll
    for (int i = 0; i < 4; ++i) {
        float* opt = out + (b0 + wv * 4 + i) * HH + h0;
#pragma unroll
        for (int j = 0; j < 8; ++j) opt[j] = acc[i][j] + bav[j];
    }
}

// ---------------- K4: igroup via masked bf16 MFMA --------------------------------
// out[b,h] += sum_e sum_{n,f} (grp[b,n]==e) * o[b,n,f] * Wa_ig[e,n,f,h]
// block: BM=64 x BN=64, 128 thr (2 waves split BN), wave-tile 64x32 of 32x32x16.
// A staged from x fp32 -> bf16 (F padded 28->32); B from prepped Wbt bf16.
// LDS XOR-swizzle: 64B rows, 16B granule ^= (row>>1)&3 (read+write sides).
__global__ __launch_bounds__(128) void k_ig(
    const float* __restrict__ x, const unsigned char* __restrict__ grpT,
    const unsigned short* __restrict__ Wbt, float* __restrict__ out)
{
    __shared__ v4u A4[2][256];        // [64 rows][4 granules] x dbuf   (8 KB)
    __shared__ v4u B4[2][1024];       // [4 e][64 h][4 granules] x dbuf (32 KB)
    __shared__ unsigned Gs_u[2048];   // [128 n][64 rows] bytes          (8 KB)

    int t = threadIdx.x;
    int b0 = (blockIdx.x >> 3) * 64;
    int h0 = (blockIdx.x & 7) * 64;
    int lane = t & 63;
    int wn = t >> 6;                  // wave n-offset: cols wn*32..
    int l31 = lane & 31, lhi = lane >> 5;

    // stage Gs once: Gs[n][row] = grpT[n][b0+row]
    const unsigned* gTu = (const unsigned*)grpT;
#pragma unroll
    for (int j = 0; j < 16; ++j) {
        int i = t + j * 128;          // = n*16 + r4
        Gs_u[i] = gTu[(size_t)(i >> 4) * (BB/4) + (b0 >> 2) + (i & 15)];
    }

    v16f acc0 = {}, acc1 = {};

    // staging for K-step n into buf
    int s_row = t >> 1, s_fh = t & 1;
    int s_sw = (s_row >> 1) & 3;
#define STAGE(nn, buf) do {                                                     \
    const float* s = x + (size_t)(b0 + s_row) * XROW + SELFW + (nn) * FF + s_fh * 16; \
    float4 fA = *(const float4*)(s + 0);                                        \
    float4 fB = *(const float4*)(s + 4);                                        \
    float4 fC = *(const float4*)(s + 8);                                        \
    float4 fD = s_fh ? make_float4(0.f,0.f,0.f,0.f) : *(const float4*)(s + 12); \
    v4u w0 = v4u{pk2(fA.x,fA.y), pk2(fA.z,fA.w), pk2(fB.x,fB.y), pk2(fB.z,fB.w)}; \
    v4u w1 = v4u{pk2(fC.x,fC.y), pk2(fC.z,fC.w), pk2(fD.x,fD.y), pk2(fD.z,fD.w)}; \
    A4[buf][s_row * 4 + ((s_fh * 2    ) ^ s_sw)] = w0;                          \
    A4[buf][s_row * 4 + ((s_fh * 2 + 1) ^ s_sw)] = w1;                          \
    _Pragma("unroll")                                                           \
    for (int j = 0; j < 8; ++j) {                                               \
        int i = t + j * 128;                                                    \
        int fg = i & 3, hh = (i >> 2) & 63, e = i >> 8;                         \
        v4u v = ((const v4u*)Wbt)[((size_t)(e * 128 + (nn)) * HH + h0 + hh) * 4 + fg]; \
        B4[buf][(e * 64 + hh) * 4 + (fg ^ ((hh >> 1) & 3))] = v;                \
    }                                                                           \
} while (0)

    STAGE(0, 0);
    int cur = 0;
    int r0 = l31, r1 = 32 + l31;
    int sw0 = (r0 >> 1) & 3, sw1 = (r1 >> 1) & 3;
    int hl = wn * 32 + l31;
    int swh = (hl >> 1) & 3;

    for (int n = 0; n < NN; ++n) {
        __syncthreads();              // buf[cur] writes visible; prev reads done
        unsigned char g0r = ((const unsigned char*)Gs_u)[n * 64 + r0];
        unsigned char g1r = ((const unsigned char*)Gs_u)[n * 64 + r1];
        v4u a00 = A4[cur][r0 * 4 + ((lhi    ) ^ sw0)];   // mb0, kh0
        v4u a01 = A4[cur][r0 * 4 + ((2 + lhi) ^ sw0)];   // mb0, kh1
        v4u a10 = A4[cur][r1 * 4 + ((lhi    ) ^ sw1)];
        v4u a11 = A4[cur][r1 * 4 + ((2 + lhi) ^ sw1)];
        v4u bf[4][2];
#pragma unroll
        for (int e = 0; e < 4; ++e) {
            bf[e][0] = B4[cur][(e * 64 + hl) * 4 + ((lhi    ) ^ swh)];
            bf[e][1] = B4[cur][(e * 64 + hl) * 4 + ((2 + lhi) ^ swh)];
        }
        if (n + 1 < NN) STAGE(n + 1, cur ^ 1);
        v4u zz = {0u, 0u, 0u, 0u};
#pragma unroll
        for (int e = 0; e < 4; ++e) {
            v4u m00 = (g0r == e) ? a00 : zz;
            v4u m01 = (g0r == e) ? a01 : zz;
            v4u m10 = (g1r == e) ? a10 : zz;
            v4u m11 = (g1r == e) ? a11 : zz;
            acc0 = __builtin_amdgcn_mfma_f32_32x32x16_bf16(as8s(m00), as8s(bf[e][0]), acc0, 0, 0, 0);
            acc0 = __builtin_amdgcn_mfma_f32_32x32x16_bf16(as8s(m01), as8s(bf[e][1]), acc0, 0, 0, 0);
            acc1 = __builtin_amdgcn_mfma_f32_32x32x16_bf16(as8s(m10), as8s(bf[e][0]), acc1, 0, 0, 0);
            acc1 = __builtin_amdgcn_mfma_f32_32x32x16_bf16(as8s(m11), as8s(bf[e][1]), acc1, 0, 0, 0);
        }
        cur ^= 1;
    }
#undef STAGE

    // C/D: col = lane&31, row = (reg&3) + 8*(reg>>2) + 4*(lane>>5)  [m74/m101]
#pragma unroll
    for (int r = 0; r < 16; ++r) {
        int rowl = (r & 3) + 8 * (r >> 2) + 4 * lhi;
        size_t i0 = (size_t)(b0 + rowl) * HH + h0 + wn * 32 + l31;
        out[i0] += acc0[r];
        out[i0 + (size_t)32 * HH] += acc1[r];
    }
}

// ---------------- launcher ----------------------------------------------------------
extern "C" void kernel_launch(void* const* d_in, const int* in_sizes, int n_in,
                              void* d_out, int out_size, void* d_ws, size_t ws_size,
                              hipStream_t stream)
{
    const float* x  = (const float*)d_in[0];
    const float* W1 = (const float*)d_in[1];
    const float* b1 = (const float*)d_in[2];
    const float* W2 = (const float*)d_in[3];
    const float* b2 = (const float*)d_in[4];
    const float* Wa = (const float*)d_in[5];
    const float* ba = (const float*)d_in[6];

    float* out     = (float*)d_out;                       // [4096,512]
    float* ig_mask = out + (size_t)BB * HH;               // [4096,4,128]
    float* og_mask = ig_mask + (size_t)BB * NI * NN;      // [4096,4,128]

    unsigned char* grp  = (unsigned char*)d_ws;                      // 512 KB
    unsigned char* grpT = grp + (size_t)BB * NN;                     // 512 KB
    float* og_em = (float*)(grpT + (size_t)BB * NN);                 // 1.75 MB
    unsigned short* Wbt = (unsigned short*)((char*)d_ws + 2883584);  // 16.78 MB

    hipMemsetAsync(ig_mask, 0, (size_t)2 * BB * NI * NN * sizeof(float), stream);

    k_prep <<<1024, 256, 0, stream>>>(Wa, Wbt);
    k_route<<<512, 256, 0, stream>>>(x, W1, b1, W2, b2, grp, grpT, ig_mask, og_mask);
    k_ogem <<<512, 256, 0, stream>>>(x, grp, og_em);
    k_dense<<<256, 256, 0, stream>>>(x, og_em, Wa, ba, out);
    k_ig   <<<512, 128, 0, stream>>>(x, grpT, Wbt, out);
}